// Round 13
// baseline (111.145 us; speedup 1.0000x reference)
//
#include <hip/hip_runtime.h>

#define NS 8192
#define EMBED 128
#define ROWCHUNK 256             // grid.y = 32 chunks of 256 rows (+1 class row)
#define NPANEL (ROWCHUNK / 32)   // 8 panels of 32 rows
#define AROW 12                  // correction-hist row stride (11 bins + 1 pad)
#define INV64K (1.0f / 65536.0f)
#define NCLS 100
#define NCAP 160                 // max class size (mean 82, 160 ~ 8.7 sigma)

typedef __bf16 bf16x8 __attribute__((ext_vector_type(8)));
typedef float f32x4 __attribute__((ext_vector_type(4)));
typedef float f32x2 __attribute__((ext_vector_type(2)));
typedef const __attribute__((address_space(1))) unsigned ag_u32;  // global
typedef __attribute__((address_space(3))) unsigned al_u32;        // LDS

// workspace layout (bytes from ws start)
#define OFF_XB  0u               // bf16 [8192][128] = 2 MiB (row-granule-XOR-swizzled)
#define OFF_GS  2097152u         // f32 [32][8192][4] col-hist partials, bins 3..6 (4 MiB)
#define OFF_GA  6291456u         // q16 u32 [8192][12] all-hist corrections (atomic)
#define OFF_POS 6684672u         // f32 [8192][12] pos-hist (11 cumulative bins + np)
#define OFF_AC  7077888u         // float[2] accum + u32 done
#define ZERO_BYTES 786448u       // OFF_GA .. OFF_AC+16 (16B multiple); gS overwritten

__device__ inline unsigned short f2bf(float f) {
  unsigned u = __float_as_uint(f);
  u += 0x7fffu + ((u >> 16) & 1u);   // round-to-nearest-even
  return (unsigned short)(u >> 16);
}
// v_med3_f32 with inline consts: 1-instr clamp (no v_pk_min/max_f32 on gfx950)
__device__ inline float clamp01(float x) { return __builtin_amdgcn_fmed3f(x, 0.f, 1.f); }

// ---- prep: fp32->bf16 convert into XOR-swizzled layout + zero accumulators ----
__global__ __launch_bounds__(256) void prep_kernel(const float* __restrict__ x,
                                                   unsigned short* __restrict__ xb,
                                                   uint4* __restrict__ zbase) {
  const int gid = blockIdx.x * 256 + threadIdx.x;   // 131072 threads: row*16+granule
  const int row = gid >> 4, g = gid & 15;
  const float4 v0 = reinterpret_cast<const float4*>(x)[row * 32 + g * 2];
  const float4 v1 = reinterpret_cast<const float4*>(x)[row * 32 + g * 2 + 1];
  uint4 o;
  o.x = (unsigned)f2bf(v0.x) | ((unsigned)f2bf(v0.y) << 16);
  o.y = (unsigned)f2bf(v0.z) | ((unsigned)f2bf(v0.w) << 16);
  o.z = (unsigned)f2bf(v1.x) | ((unsigned)f2bf(v1.y) << 16);
  o.w = (unsigned)f2bf(v1.z) | ((unsigned)f2bf(v1.w) << 16);
  reinterpret_cast<uint4*>(xb)[row * 16 + (g ^ (row & 7))] = o;
  if (gid < (int)(ZERO_BYTES / 16u)) zbase[gid] = make_uint4(0u, 0u, 0u, 0u);
}

// ---- main kernel (r8 hot path; ROWCHUNK 512->256 for scheduling slack) ----
// Grid (128, 33). by < 32: label-free all-pairs histogram (bins 3..6 exact in
// registers, 8 VALU/pair; rare path thr 0.4 handles gA tails + diagonal).
// r8's 2048-block grid was EXACTLY 8 blocks/CU (zero slack) yet occupancy sat
// at ~44% (~3.6 blocks/CU resident) with VALU 45% / LDS ~42% both half-idle ->
// wave-starved. 4096 blocks (16 queued/CU) give the scheduler backfill.
// by == 32, bx < 100: independent class blocks computing the EXACT positive
// histogram sparsely (same MFMA on same bf16 data -> bit-identical dots).
__global__ __launch_bounds__(256, 8) void fastap_main_kernel(
    const unsigned short* __restrict__ xb,
    const int* __restrict__ labels,
    float* __restrict__ gS, unsigned* __restrict__ gA,
    float* __restrict__ gPos) {
  __shared__ __align__(16) unsigned short sA[2][32 * 128];  // 2 x 8KB row panels
  __shared__ int sList[NCAP];
  __shared__ int sCnt;

  const int tid  = threadIdx.x;
  const int wave = tid >> 6;
  const int lane = tid & 63;
  const int l16  = lane & 15;
  const int quad = lane >> 4;

  if (blockIdx.y == NS / ROWCHUNK) {
    // ================= class blocks: exact sparse positive pass =============
    if (blockIdx.x >= NCLS) return;
    const int cls = blockIdx.x;

    // phase 1: ballot-compact this class's member rows into sList
    if (tid == 0) sCnt = 0;
    __syncthreads();
    for (int base = wave * 64; base < NS; base += 256) {
      const int lab = labels[base + lane];
      const unsigned long long m = __ballot(lab == cls);
      if (m) {
        const int fl = (int)__builtin_ctzll(m);
        int wb = 0;
        if (lane == fl) wb = atomicAdd(&sCnt, (int)__popcll(m));
        wb = __shfl(wb, fl, 64);
        if (lab == cls) {
          const int rank = (int)__popcll(m & ((1ull << lane) - 1ull));
          const int idx = wb + rank;
          if (idx < NCAP) sList[idx] = base + lane;
        }
      }
    }
    __syncthreads();
    const int nc = min(sCnt, NCAP);

    // phase 2: Gram + 11 cumulative pos-bins, reading xb straight from global
    // (L2-resident). Granule XOR (kb*4+quad)^(R&7) recovers logical granule
    // kb*4+quad -> operands bit-identical to the main path's MFMA.
    for (int cT = wave * 16; cT < nc; cT += 64) {
      const int sc = cT + l16;                   // class-local col
      const int Rc = sList[(sc < nc) ? sc : cT]; // dummy for overrun lanes
      bf16x8 bfr[4];
      #pragma unroll
      for (int kb = 0; kb < 4; ++kb) {
        const int pg = (kb * 4 + quad) ^ (Rc & 7);
        bfr[kb] = *reinterpret_cast<const bf16x8*>(&xb[Rc * 128 + pg * 8]);
      }

      f32x2 Hp0 = {0.f, 0.f}, Hp1 = {0.f, 0.f}, Hp2 = {0.f, 0.f};
      f32x2 Hp3 = {0.f, 0.f}, Hp4 = {0.f, 0.f};
      float Hp10 = 0.f;

      for (int rT = 0; rT < nc; rT += 16) {
        const int rl = rT + l16;
        const int Rr = sList[(rl < nc) ? rl : rT];  // dummy rows skipped below
        f32x4 acc = {0.f, 0.f, 0.f, 0.f};
        #pragma unroll
        for (int kb = 0; kb < 4; ++kb) {
          const int pg = (kb * 4 + quad) ^ (Rr & 7);
          const bf16x8 afr =
              *reinterpret_cast<const bf16x8*>(&xb[Rr * 128 + pg * 8]);
          acc = __builtin_amdgcn_mfma_f32_16x16x32_bf16(afr, bfr[kb], acc, 0, 0, 0);
        }
        #pragma unroll
        for (int r = 0; r < 4; ++r) {
          const int row = rT + quad * 4 + r;       // class-local row
          if (row == sc || row >= nc) continue;    // skip self + pad rows
          const float a = acc[r];
          const f32x2 av = {a, a};
          f32x2 t;
          t = __builtin_elementwise_fma(av, (f32x2){5.f, 5.f}, (f32x2){-4.f, -3.f});
          Hp0 += (f32x2){clamp01(t.x), clamp01(t.y)};
          t = __builtin_elementwise_fma(av, (f32x2){5.f, 5.f}, (f32x2){-2.f, -1.f});
          Hp1 += (f32x2){clamp01(t.x), clamp01(t.y)};
          t = __builtin_elementwise_fma(av, (f32x2){5.f, 5.f}, (f32x2){0.f, 1.f});
          Hp2 += (f32x2){clamp01(t.x), clamp01(t.y)};
          t = __builtin_elementwise_fma(av, (f32x2){5.f, 5.f}, (f32x2){2.f, 3.f});
          Hp3 += (f32x2){clamp01(t.x), clamp01(t.y)};
          t = __builtin_elementwise_fma(av, (f32x2){5.f, 5.f}, (f32x2){4.f, 5.f});
          Hp4 += (f32x2){clamp01(t.x), clamp01(t.y)};
          Hp10 += clamp01(fmaf(a, 5.f, 6.f));
        }
      }

      // reduce across the 4 quads sharing each col (lane ^16, ^32)
      #pragma unroll
      for (int m = 16; m < 64; m <<= 1) {
        Hp0.x += __shfl_xor(Hp0.x, m, 64); Hp0.y += __shfl_xor(Hp0.y, m, 64);
        Hp1.x += __shfl_xor(Hp1.x, m, 64); Hp1.y += __shfl_xor(Hp1.y, m, 64);
        Hp2.x += __shfl_xor(Hp2.x, m, 64); Hp2.y += __shfl_xor(Hp2.y, m, 64);
        Hp3.x += __shfl_xor(Hp3.x, m, 64); Hp3.y += __shfl_xor(Hp3.y, m, 64);
        Hp4.x += __shfl_xor(Hp4.x, m, 64); Hp4.y += __shfl_xor(Hp4.y, m, 64);
        Hp10  += __shfl_xor(Hp10,  m, 64);
      }

      if (quad == 0 && sc < nc) {               // plain stores; kernel boundary
        float4* gp = reinterpret_cast<float4*>(gPos + sList[sc] * 12);  // fences
        gp[0] = make_float4(Hp0.x, Hp0.y, Hp1.x, Hp1.y);   // bins 0..3
        gp[1] = make_float4(Hp2.x, Hp2.y, Hp3.x, Hp3.y);   // bins 4..7
        gp[2] = make_float4(Hp4.x, Hp4.y, Hp10, (float)(nc - 1));  // 8,9,10,np
      }
    }
    return;
  }

  // ================= compute blocks: label-free all-pairs histogram =========
  const int colBase  = blockIdx.x * 64;       // 128 col strips
  const int rowChunk = blockIdx.y * ROWCHUNK; // 32 row chunks

  // fixed B fragments: this wave's 16 cols, K=128 (jcol&7 == l16&7)
  const int jcol = colBase + wave * 16 + l16;
  bf16x8 bfr[4];
  #pragma unroll
  for (int kb = 0; kb < 4; ++kb) {
    const int pg = (kb * 4 + quad) ^ (l16 & 7);
    bfr[kb] = *reinterpret_cast<const bf16x8*>(&xb[jcol * 128 + pg * 8]);
  }

  f32x2 C01 = {0.f, 0.f}, C23 = {0.f, 0.f};   // bins 3,4 / 5,6

  // A-frag ds_read offsets within a 16-row sub-panel (row&7 == l16&7)
  int aOff[4];
  #pragma unroll
  for (int kb = 0; kb < 4; ++kb)
    aOff[kb] = l16 * 128 + (((kb * 4 + quad) ^ (l16 & 7)) << 3);

  // stage panel p's 32 rows (8KB) into buffer b: 2 x 16B per thread
  const unsigned short* xrb = xb + rowChunk * 128;
  auto stage = [&](int p, int b) {
    const unsigned short* src = xrb + p * (32 * 128);
    __builtin_amdgcn_global_load_lds((ag_u32*)(src + tid * 8),
                                     (al_u32*)(&sA[b][tid * 8]), 16, 0, 0);
    __builtin_amdgcn_global_load_lds((ag_u32*)(src + (tid + 256) * 8),
                                     (al_u32*)(&sA[b][(tid + 256) * 8]), 16, 0, 0);
  };

  // one 16-row x 16-col tile; lcr = row offset within chunk (mult of 16)
  auto tile16 = [&](const unsigned short* ap, int lcr) {
    bf16x8 a0 = *reinterpret_cast<const bf16x8*>(&ap[aOff[0]]);
    bf16x8 a1 = *reinterpret_cast<const bf16x8*>(&ap[aOff[1]]);
    bf16x8 a2 = *reinterpret_cast<const bf16x8*>(&ap[aOff[2]]);
    bf16x8 a3 = *reinterpret_cast<const bf16x8*>(&ap[aOff[3]]);
    f32x4 acc = {0.f, 0.f, 0.f, 0.f};    // single chain: 8 waves/SIMD hide latency
    acc = __builtin_amdgcn_mfma_f32_16x16x32_bf16(a0, bfr[0], acc, 0, 0, 0);
    acc = __builtin_amdgcn_mfma_f32_16x16x32_bf16(a1, bfr[1], acc, 0, 0, 0);
    acc = __builtin_amdgcn_mfma_f32_16x16x32_bf16(a2, bfr[2], acc, 0, 0, 0);
    acc = __builtin_amdgcn_mfma_f32_16x16x32_bf16(a3, bfr[3], acc, 0, 0, 0);

    // fast path: 2 pk_fma + 4 med3 + 2 pk_add per pair. Register bins 3..6
    // are EXACT for all a: H[b] = clamp01(5a + (b-4)).
    #pragma unroll
    for (int r = 0; r < 4; ++r) {              // D: row = quad*4+r, col = l16
      const float a = acc[r];                  // cos(i, jcol)
      const f32x2 av = {a, a};
      f32x2 d01 = __builtin_elementwise_fma(av, (f32x2){5.f, 5.f},
                                            (f32x2){-1.f, 0.f});
      f32x2 d23 = __builtin_elementwise_fma(av, (f32x2){5.f, 5.f},
                                            (f32x2){1.f, 2.f});
      d01 = (f32x2){clamp01(d01.x), clamp01(d01.y)};
      d23 = (f32x2){clamp01(d23.x), clamp01(d23.y)};
      C01 += d01; C23 += d23;
    }

    // rare check per 4 pairs, thr 0.4 (wave-trigger ~0.2%; r6 lesson: branch
    // cost is at EXEC-MASK granularity -> keep per-pair P ~ 1e-5)
    const float mabs = fmaxf(fmaxf(fabsf(acc[0]), fabsf(acc[1])),
                             fmaxf(fabsf(acc[2]), fabsf(acc[3])));
    if (__builtin_expect(mabs > 0.4f, 0)) {
      #pragma unroll
      for (int r = 0; r < 4; ++r) {
        const float a = acc[r];
        if (fabsf(a) <= 0.4f) continue;
        const int i = rowChunk + lcr + quad * 4 + r;
        // recompute (bit-identical to fast path)
        const float d0 = clamp01(fmaf(a, 5.f, -1.f));
        const float d1 = clamp01(a * 5.f);
        const float d2 = clamp01(fmaf(a, 5.f, 1.f));
        const float d3 = clamp01(fmaf(a, 5.f, 2.f));
        if (i == jcol) {
          // diagonal: cancel fast contributions + bins>=7 base (+1)
          C01 -= (f32x2){d0, d1};  C23 -= (f32x2){d2, d3};
          #pragma unroll
          for (int k = 7; k <= 10; ++k)
            atomicAdd(&gA[jcol * AROW + k], (unsigned)(-65536));
        } else {
          const float t = fmaf(a, -5.f, 5.f);
          #pragma unroll
          for (int k = 0; k <= 2; ++k) {       // assumed cumulative 0
            const float v = clamp01((float)(k + 1) - t);
            const int q = (int)(v * 65536.f + 0.5f);
            if (q) atomicAdd(&gA[jcol * AROW + k], (unsigned)q);
          }
          #pragma unroll
          for (int k = 7; k <= 10; ++k) {      // assumed cumulative 1
            const float v = clamp01((float)(k + 1) - t) - 1.f;
            const int q = (int)(v * 65536.f - 0.5f);
            if (q) atomicAdd(&gA[jcol * AROW + k], (unsigned)q);
          }
        }
      }
    }
  };

  stage(0, 0);
  __syncthreads();             // panel 0 drained

  #pragma unroll 1
  for (int p = 0; p < NPANEL; ++p) {
    const int cur = p & 1;
    if (p + 1 < NPANEL) stage(p + 1, cur ^ 1);   // async DMA behind this panel
    tile16(&sA[cur][0],        p * 32);
    tile16(&sA[cur][16 * 128], p * 32 + 16);
    __syncthreads();
  }

  // reduce across the 4 quads sharing each column (lane ^16, ^32)
  #pragma unroll
  for (int m = 16; m < 64; m <<= 1) {
    C01.x += __shfl_xor(C01.x, m, 64); C01.y += __shfl_xor(C01.y, m, 64);
    C23.x += __shfl_xor(C23.x, m, 64); C23.y += __shfl_xor(C23.y, m, 64);
  }

  if (quad == 0) {
    const int slot = blockIdx.y;                 // 32 partial slots, no atomics
    const float4 cv = make_float4(C01.x, C01.y, C23.x, C23.y);  // bins 3,4,5,6
    reinterpret_cast<float4*>(gS)[slot * NS + jcol] = cv;
  }
}

// ---- epilogue: sum 32 partials + corrections + exact pos-hist -> AP + loss ----
__global__ __launch_bounds__(256) void epilogue_kernel(
    const float* __restrict__ gS, const unsigned* __restrict__ gA,
    const float* __restrict__ gPos,
    float* __restrict__ accum, unsigned* __restrict__ done,
    float* __restrict__ out) {
  const int i = blockIdx.x * 256 + threadIdx.x;
  const float4* gS4 = reinterpret_cast<const float4*>(gS);
  float4 Cs = make_float4(0.f, 0.f, 0.f, 0.f);
  #pragma unroll 8
  for (int c = 0; c < 32; ++c) {
    const float4 u = gS4[c * NS + i];
    Cs.x += u.x; Cs.y += u.y; Cs.z += u.z; Cs.w += u.w;
  }
  const float CsA[4] = {Cs.x, Cs.y, Cs.z, Cs.w};

  const float4* gp4 = reinterpret_cast<const float4*>(gPos + i * 12);
  const float4 h0 = gp4[0], h1 = gp4[1], h2 = gp4[2];
  const float Hp[11] = {h0.x, h0.y, h0.z, h0.w, h1.x, h1.y,
                        h1.z, h1.w, h2.x, h2.y, h2.z};
  const int np = (int)h2.w;

  float ap = 0.f, val = 0.f, HpPrev = 0.f;
  #pragma unroll
  for (int b = 0; b <= 10; ++b) {
    const float baseH = (b < 3) ? 0.f : (b < 7) ? CsA[b - 3] : 8192.f;
    const float H = baseH + (float)(int)gA[i * AROW + b] * INV64K;
    const float hp = Hp[b] - HpPrev;
    HpPrev = Hp[b];
    if (H > 1e-6f) ap += hp * Hp[b] / H;
  }
  if (np > 0) { ap /= (float)np; val = 1.f; } else ap = 0.f;

  __shared__ float sa[256], sv[256];
  sa[threadIdx.x] = ap; sv[threadIdx.x] = val;
  __syncthreads();
  for (int s = 128; s > 0; s >>= 1) {
    if (threadIdx.x < s) {
      sa[threadIdx.x] += sa[threadIdx.x + s];
      sv[threadIdx.x] += sv[threadIdx.x + s];
    }
    __syncthreads();
  }
  if (threadIdx.x == 0) {
    atomicAdd(&accum[0], sa[0]);
    atomicAdd(&accum[1], sv[0]);
    __threadfence();
    const unsigned prev = atomicAdd(done, 1u);
    if (prev == gridDim.x - 1) {
      const float a = atomicAdd(&accum[0], 0.f);   // coherent reads
      const float c = atomicAdd(&accum[1], 0.f);
      out[0] = 1.f - (c > 0.f ? a / c : 0.f);
    }
  }
}

extern "C" void kernel_launch(void* const* d_in, const int* in_sizes, int n_in,
                              void* d_out, int out_size, void* d_ws, size_t ws_size,
                              hipStream_t stream) {
  const float* x      = (const float*)d_in[0];
  const int*   labels = (const int*)d_in[1];
  float* out = (float*)d_out;

  char* ws = (char*)d_ws;
  unsigned short* xb = (unsigned short*)(ws + OFF_XB);
  float*    gS    = (float*)(ws + OFF_GS);
  unsigned* gA    = (unsigned*)(ws + OFF_GA);
  float*    gPos  = (float*)(ws + OFF_POS);
  float*    accum = (float*)(ws + OFF_AC);
  unsigned* done  = (unsigned*)(ws + OFF_AC + 8);

  prep_kernel<<<512, 256, 0, stream>>>(x, xb, (uint4*)(ws + OFF_GA));
  fastap_main_kernel<<<dim3(NS / 64, NS / ROWCHUNK + 1), 256, 0, stream>>>(
      xb, labels, gS, gA, gPos);
  epilogue_kernel<<<NS / 256, 256, 0, stream>>>(gS, gA, gPos, accum, done, out);
}

// Round 14
// 106.920 us; speedup vs baseline: 1.0395x; 1.0395x over previous
//
#include <hip/hip_runtime.h>

#define NS 8192
#define EMBED 128
#define ROWCHUNK 512             // grid.y = 16 chunks of 512 rows (+1 class row)
#define NPANEL (ROWCHUNK / 32)   // 16 panels of 32 rows
#define AROW 12                  // correction-hist row stride (11 bins + 1 pad)
#define INV64K (1.0f / 65536.0f)
#define NCLS 100
#define NCAP 160                 // max class size (mean 82, 160 ~ 8.7 sigma)

typedef __bf16 bf16x8 __attribute__((ext_vector_type(8)));
typedef float f32x4 __attribute__((ext_vector_type(4)));
typedef float f32x2 __attribute__((ext_vector_type(2)));
typedef const __attribute__((address_space(1))) unsigned ag_u32;  // global
typedef __attribute__((address_space(3))) unsigned al_u32;        // LDS

// workspace layout (bytes from ws start)
#define OFF_XB  0u               // bf16 [8192][128] = 2 MiB (row-granule-XOR-swizzled)
#define OFF_GS  2097152u         // f32 [16][8192][4] col-hist partials, bins 3..6 (2 MiB)
#define OFF_GA  4194304u         // q16 u32 [8192][12] all-hist corrections (atomic)
#define OFF_POS 4587520u         // f32 [8192][12] pos-hist (11 cumulative bins + np)
#define OFF_AC  4980736u         // float[2] accum + u32 done
#define ZERO_BYTES 786448u       // OFF_GA .. OFF_AC+16 (16B multiple); gS overwritten

__device__ inline unsigned short f2bf(float f) {
  unsigned u = __float_as_uint(f);
  u += 0x7fffu + ((u >> 16) & 1u);   // round-to-nearest-even
  return (unsigned short)(u >> 16);
}
// v_med3_f32 with inline consts: 1-instr clamp (no v_pk_min/max_f32 on gfx950)
__device__ inline float clamp01(float x) { return __builtin_amdgcn_fmed3f(x, 0.f, 1.f); }

// ---- prep: fp32->bf16 convert into XOR-swizzled layout + zero accumulators ----
__global__ __launch_bounds__(256) void prep_kernel(const float* __restrict__ x,
                                                   unsigned short* __restrict__ xb,
                                                   uint4* __restrict__ zbase) {
  const int gid = blockIdx.x * 256 + threadIdx.x;   // 131072 threads: row*16+granule
  const int row = gid >> 4, g = gid & 15;
  const float4 v0 = reinterpret_cast<const float4*>(x)[row * 32 + g * 2];
  const float4 v1 = reinterpret_cast<const float4*>(x)[row * 32 + g * 2 + 1];
  uint4 o;
  o.x = (unsigned)f2bf(v0.x) | ((unsigned)f2bf(v0.y) << 16);
  o.y = (unsigned)f2bf(v0.z) | ((unsigned)f2bf(v0.w) << 16);
  o.z = (unsigned)f2bf(v1.x) | ((unsigned)f2bf(v1.y) << 16);
  o.w = (unsigned)f2bf(v1.z) | ((unsigned)f2bf(v1.w) << 16);
  reinterpret_cast<uint4*>(xb)[row * 16 + (g ^ (row & 7))] = o;
  if (gid < (int)(ZERO_BYTES / 16u)) zbase[gid] = make_uint4(0u, 0u, 0u, 0u);
}

// ---- main kernel (r8 structure: best verified, main 48.0-48.7 us) ----
// Grid (128, 17). by < 16: label-free all-pairs histogram (bins 3..6 exact in
// registers, 8 VALU/pair; rare path thr 0.4 handles gA tails + diagonal).
// by == 16, bx < 100: independent class blocks computing the EXACT positive
// histogram sparsely (per-class Gram via the same MFMA on the same bf16 data ->
// bit-identical dots), written to gPos. No block waits on any other block.
__global__ __launch_bounds__(256, 8) void fastap_main_kernel(
    const unsigned short* __restrict__ xb,
    const int* __restrict__ labels,
    float* __restrict__ gS, unsigned* __restrict__ gA,
    float* __restrict__ gPos) {
  __shared__ __align__(16) unsigned short sA[2][32 * 128];  // 2 x 8KB row panels
  __shared__ int sList[NCAP];
  __shared__ int sCnt;

  const int tid  = threadIdx.x;
  const int wave = tid >> 6;
  const int lane = tid & 63;
  const int l16  = lane & 15;
  const int quad = lane >> 4;

  if (blockIdx.y == NS / ROWCHUNK) {
    // ================= class blocks: exact sparse positive pass =============
    if (blockIdx.x >= NCLS) return;
    const int cls = blockIdx.x;

    // phase 1: ballot-compact this class's member rows into sList
    if (tid == 0) sCnt = 0;
    __syncthreads();
    for (int base = wave * 64; base < NS; base += 256) {
      const int lab = labels[base + lane];
      const unsigned long long m = __ballot(lab == cls);
      if (m) {
        const int fl = (int)__builtin_ctzll(m);
        int wb = 0;
        if (lane == fl) wb = atomicAdd(&sCnt, (int)__popcll(m));
        wb = __shfl(wb, fl, 64);
        if (lab == cls) {
          const int rank = (int)__popcll(m & ((1ull << lane) - 1ull));
          const int idx = wb + rank;
          if (idx < NCAP) sList[idx] = base + lane;
        }
      }
    }
    __syncthreads();
    const int nc = min(sCnt, NCAP);

    // phase 2: Gram + 11 cumulative pos-bins, reading xb straight from global
    // (L2-resident). Granule XOR (kb*4+quad)^(R&7) recovers logical granule
    // kb*4+quad -> operands bit-identical to the main path's MFMA.
    for (int cT = wave * 16; cT < nc; cT += 64) {
      const int sc = cT + l16;                   // class-local col
      const int Rc = sList[(sc < nc) ? sc : cT]; // dummy for overrun lanes
      bf16x8 bfr[4];
      #pragma unroll
      for (int kb = 0; kb < 4; ++kb) {
        const int pg = (kb * 4 + quad) ^ (Rc & 7);
        bfr[kb] = *reinterpret_cast<const bf16x8*>(&xb[Rc * 128 + pg * 8]);
      }

      f32x2 Hp0 = {0.f, 0.f}, Hp1 = {0.f, 0.f}, Hp2 = {0.f, 0.f};
      f32x2 Hp3 = {0.f, 0.f}, Hp4 = {0.f, 0.f};
      float Hp10 = 0.f;

      for (int rT = 0; rT < nc; rT += 16) {
        const int rl = rT + l16;
        const int Rr = sList[(rl < nc) ? rl : rT];  // dummy rows skipped below
        f32x4 acc = {0.f, 0.f, 0.f, 0.f};
        #pragma unroll
        for (int kb = 0; kb < 4; ++kb) {
          const int pg = (kb * 4 + quad) ^ (Rr & 7);
          const bf16x8 afr =
              *reinterpret_cast<const bf16x8*>(&xb[Rr * 128 + pg * 8]);
          acc = __builtin_amdgcn_mfma_f32_16x16x32_bf16(afr, bfr[kb], acc, 0, 0, 0);
        }
        #pragma unroll
        for (int r = 0; r < 4; ++r) {
          const int row = rT + quad * 4 + r;       // class-local row
          if (row == sc || row >= nc) continue;    // skip self + pad rows
          const float a = acc[r];
          const f32x2 av = {a, a};
          f32x2 t;
          t = __builtin_elementwise_fma(av, (f32x2){5.f, 5.f}, (f32x2){-4.f, -3.f});
          Hp0 += (f32x2){clamp01(t.x), clamp01(t.y)};
          t = __builtin_elementwise_fma(av, (f32x2){5.f, 5.f}, (f32x2){-2.f, -1.f});
          Hp1 += (f32x2){clamp01(t.x), clamp01(t.y)};
          t = __builtin_elementwise_fma(av, (f32x2){5.f, 5.f}, (f32x2){0.f, 1.f});
          Hp2 += (f32x2){clamp01(t.x), clamp01(t.y)};
          t = __builtin_elementwise_fma(av, (f32x2){5.f, 5.f}, (f32x2){2.f, 3.f});
          Hp3 += (f32x2){clamp01(t.x), clamp01(t.y)};
          t = __builtin_elementwise_fma(av, (f32x2){5.f, 5.f}, (f32x2){4.f, 5.f});
          Hp4 += (f32x2){clamp01(t.x), clamp01(t.y)};
          Hp10 += clamp01(fmaf(a, 5.f, 6.f));
        }
      }

      // reduce across the 4 quads sharing each col (lane ^16, ^32)
      #pragma unroll
      for (int m = 16; m < 64; m <<= 1) {
        Hp0.x += __shfl_xor(Hp0.x, m, 64); Hp0.y += __shfl_xor(Hp0.y, m, 64);
        Hp1.x += __shfl_xor(Hp1.x, m, 64); Hp1.y += __shfl_xor(Hp1.y, m, 64);
        Hp2.x += __shfl_xor(Hp2.x, m, 64); Hp2.y += __shfl_xor(Hp2.y, m, 64);
        Hp3.x += __shfl_xor(Hp3.x, m, 64); Hp3.y += __shfl_xor(Hp3.y, m, 64);
        Hp4.x += __shfl_xor(Hp4.x, m, 64); Hp4.y += __shfl_xor(Hp4.y, m, 64);
        Hp10  += __shfl_xor(Hp10,  m, 64);
      }

      if (quad == 0 && sc < nc) {               // plain stores; kernel boundary
        float4* gp = reinterpret_cast<float4*>(gPos + sList[sc] * 12);  // fences
        gp[0] = make_float4(Hp0.x, Hp0.y, Hp1.x, Hp1.y);   // bins 0..3
        gp[1] = make_float4(Hp2.x, Hp2.y, Hp3.x, Hp3.y);   // bins 4..7
        gp[2] = make_float4(Hp4.x, Hp4.y, Hp10, (float)(nc - 1));  // 8,9,10,np
      }
    }
    return;
  }

  // ================= compute blocks: label-free all-pairs histogram =========
  const int colBase  = blockIdx.x * 64;       // 128 col strips
  const int rowChunk = blockIdx.y * ROWCHUNK; // 16 row chunks

  // fixed B fragments: this wave's 16 cols, K=128 (jcol&7 == l16&7)
  const int jcol = colBase + wave * 16 + l16;
  bf16x8 bfr[4];
  #pragma unroll
  for (int kb = 0; kb < 4; ++kb) {
    const int pg = (kb * 4 + quad) ^ (l16 & 7);
    bfr[kb] = *reinterpret_cast<const bf16x8*>(&xb[jcol * 128 + pg * 8]);
  }

  f32x2 C01 = {0.f, 0.f}, C23 = {0.f, 0.f};   // bins 3,4 / 5,6

  // A-frag ds_read offsets within a 16-row sub-panel (row&7 == l16&7)
  int aOff[4];
  #pragma unroll
  for (int kb = 0; kb < 4; ++kb)
    aOff[kb] = l16 * 128 + (((kb * 4 + quad) ^ (l16 & 7)) << 3);

  // stage panel p's 32 rows (8KB) into buffer b: 2 x 16B per thread
  const unsigned short* xrb = xb + rowChunk * 128;
  auto stage = [&](int p, int b) {
    const unsigned short* src = xrb + p * (32 * 128);
    __builtin_amdgcn_global_load_lds((ag_u32*)(src + tid * 8),
                                     (al_u32*)(&sA[b][tid * 8]), 16, 0, 0);
    __builtin_amdgcn_global_load_lds((ag_u32*)(src + (tid + 256) * 8),
                                     (al_u32*)(&sA[b][(tid + 256) * 8]), 16, 0, 0);
  };

  // one 16-row x 16-col tile; lcr = row offset within chunk (mult of 16)
  auto tile16 = [&](const unsigned short* ap, int lcr) {
    bf16x8 a0 = *reinterpret_cast<const bf16x8*>(&ap[aOff[0]]);
    bf16x8 a1 = *reinterpret_cast<const bf16x8*>(&ap[aOff[1]]);
    bf16x8 a2 = *reinterpret_cast<const bf16x8*>(&ap[aOff[2]]);
    bf16x8 a3 = *reinterpret_cast<const bf16x8*>(&ap[aOff[3]]);
    f32x4 acc = {0.f, 0.f, 0.f, 0.f};    // single chain: 8 waves/SIMD hide latency
    acc = __builtin_amdgcn_mfma_f32_16x16x32_bf16(a0, bfr[0], acc, 0, 0, 0);
    acc = __builtin_amdgcn_mfma_f32_16x16x32_bf16(a1, bfr[1], acc, 0, 0, 0);
    acc = __builtin_amdgcn_mfma_f32_16x16x32_bf16(a2, bfr[2], acc, 0, 0, 0);
    acc = __builtin_amdgcn_mfma_f32_16x16x32_bf16(a3, bfr[3], acc, 0, 0, 0);

    // fast path: 2 pk_fma + 4 med3 + 2 pk_add per pair. Register bins 3..6
    // are EXACT for all a: H[b] = clamp01(5a + (b-4)).
    #pragma unroll
    for (int r = 0; r < 4; ++r) {              // D: row = quad*4+r, col = l16
      const float a = acc[r];                  // cos(i, jcol)
      const f32x2 av = {a, a};
      f32x2 d01 = __builtin_elementwise_fma(av, (f32x2){5.f, 5.f},
                                            (f32x2){-1.f, 0.f});
      f32x2 d23 = __builtin_elementwise_fma(av, (f32x2){5.f, 5.f},
                                            (f32x2){1.f, 2.f});
      d01 = (f32x2){clamp01(d01.x), clamp01(d01.y)};
      d23 = (f32x2){clamp01(d23.x), clamp01(d23.y)};
      C01 += d01; C23 += d23;
    }

    // rare check per 4 pairs, thr 0.4 (wave-trigger ~0.2%; r6 lesson: branch
    // cost is at EXEC-MASK granularity -> keep per-pair P ~ 1e-5)
    const float mabs = fmaxf(fmaxf(fabsf(acc[0]), fabsf(acc[1])),
                             fmaxf(fabsf(acc[2]), fabsf(acc[3])));
    if (__builtin_expect(mabs > 0.4f, 0)) {
      #pragma unroll
      for (int r = 0; r < 4; ++r) {
        const float a = acc[r];
        if (fabsf(a) <= 0.4f) continue;
        const int i = rowChunk + lcr + quad * 4 + r;
        // recompute (bit-identical to fast path)
        const float d0 = clamp01(fmaf(a, 5.f, -1.f));
        const float d1 = clamp01(a * 5.f);
        const float d2 = clamp01(fmaf(a, 5.f, 1.f));
        const float d3 = clamp01(fmaf(a, 5.f, 2.f));
        if (i == jcol) {
          // diagonal: cancel fast contributions + bins>=7 base (+1)
          C01 -= (f32x2){d0, d1};  C23 -= (f32x2){d2, d3};
          #pragma unroll
          for (int k = 7; k <= 10; ++k)
            atomicAdd(&gA[jcol * AROW + k], (unsigned)(-65536));
        } else {
          const float t = fmaf(a, -5.f, 5.f);
          #pragma unroll
          for (int k = 0; k <= 2; ++k) {       // assumed cumulative 0
            const float v = clamp01((float)(k + 1) - t);
            const int q = (int)(v * 65536.f + 0.5f);
            if (q) atomicAdd(&gA[jcol * AROW + k], (unsigned)q);
          }
          #pragma unroll
          for (int k = 7; k <= 10; ++k) {      // assumed cumulative 1
            const float v = clamp01((float)(k + 1) - t) - 1.f;
            const int q = (int)(v * 65536.f - 0.5f);
            if (q) atomicAdd(&gA[jcol * AROW + k], (unsigned)q);
          }
        }
      }
    }
  };

  stage(0, 0);
  __syncthreads();             // panel 0 drained

  #pragma unroll 1
  for (int p = 0; p < NPANEL; ++p) {
    const int cur = p & 1;
    if (p + 1 < NPANEL) stage(p + 1, cur ^ 1);   // async DMA behind this panel
    tile16(&sA[cur][0],        p * 32);
    tile16(&sA[cur][16 * 128], p * 32 + 16);
    __syncthreads();
  }

  // reduce across the 4 quads sharing each column (lane ^16, ^32)
  #pragma unroll
  for (int m = 16; m < 64; m <<= 1) {
    C01.x += __shfl_xor(C01.x, m, 64); C01.y += __shfl_xor(C01.y, m, 64);
    C23.x += __shfl_xor(C23.x, m, 64); C23.y += __shfl_xor(C23.y, m, 64);
  }

  if (quad == 0) {
    const int slot = blockIdx.y;                 // 16 partial slots, no atomics
    const float4 cv = make_float4(C01.x, C01.y, C23.x, C23.y);  // bins 3,4,5,6
    reinterpret_cast<float4*>(gS)[slot * NS + jcol] = cv;
  }
}

// ---- epilogue: sum 16 partials + corrections + exact pos-hist -> AP + loss ----
__global__ __launch_bounds__(256) void epilogue_kernel(
    const float* __restrict__ gS, const unsigned* __restrict__ gA,
    const float* __restrict__ gPos,
    float* __restrict__ accum, unsigned* __restrict__ done,
    float* __restrict__ out) {
  const int i = blockIdx.x * 256 + threadIdx.x;
  const float4* gS4 = reinterpret_cast<const float4*>(gS);
  float4 Cs = make_float4(0.f, 0.f, 0.f, 0.f);
  #pragma unroll 4
  for (int c = 0; c < 16; ++c) {
    const float4 u = gS4[c * NS + i];
    Cs.x += u.x; Cs.y += u.y; Cs.z += u.z; Cs.w += u.w;
  }
  const float CsA[4] = {Cs.x, Cs.y, Cs.z, Cs.w};

  const float4* gp4 = reinterpret_cast<const float4*>(gPos + i * 12);
  const float4 h0 = gp4[0], h1 = gp4[1], h2 = gp4[2];
  const float Hp[11] = {h0.x, h0.y, h0.z, h0.w, h1.x, h1.y,
                        h1.z, h1.w, h2.x, h2.y, h2.z};
  const int np = (int)h2.w;

  float ap = 0.f, val = 0.f, HpPrev = 0.f;
  #pragma unroll
  for (int b = 0; b <= 10; ++b) {
    const float baseH = (b < 3) ? 0.f : (b < 7) ? CsA[b - 3] : 8192.f;
    const float H = baseH + (float)(int)gA[i * AROW + b] * INV64K;
    const float hp = Hp[b] - HpPrev;
    HpPrev = Hp[b];
    if (H > 1e-6f) ap += hp * Hp[b] / H;
  }
  if (np > 0) { ap /= (float)np; val = 1.f; } else ap = 0.f;

  __shared__ float sa[256], sv[256];
  sa[threadIdx.x] = ap; sv[threadIdx.x] = val;
  __syncthreads();
  for (int s = 128; s > 0; s >>= 1) {
    if (threadIdx.x < s) {
      sa[threadIdx.x] += sa[threadIdx.x + s];
      sv[threadIdx.x] += sv[threadIdx.x + s];
    }
    __syncthreads();
  }
  if (threadIdx.x == 0) {
    atomicAdd(&accum[0], sa[0]);
    atomicAdd(&accum[1], sv[0]);
    __threadfence();
    const unsigned prev = atomicAdd(done, 1u);
    if (prev == gridDim.x - 1) {
      const float a = atomicAdd(&accum[0], 0.f);   // coherent reads
      const float c = atomicAdd(&accum[1], 0.f);
      out[0] = 1.f - (c > 0.f ? a / c : 0.f);
    }
  }
}

extern "C" void kernel_launch(void* const* d_in, const int* in_sizes, int n_in,
                              void* d_out, int out_size, void* d_ws, size_t ws_size,
                              hipStream_t stream) {
  const float* x      = (const float*)d_in[0];
  const int*   labels = (const int*)d_in[1];
  float* out = (float*)d_out;

  char* ws = (char*)d_ws;
  unsigned short* xb = (unsigned short*)(ws + OFF_XB);
  float*    gS    = (float*)(ws + OFF_GS);
  unsigned* gA    = (unsigned*)(ws + OFF_GA);
  float*    gPos  = (float*)(ws + OFF_POS);
  float*    accum = (float*)(ws + OFF_AC);
  unsigned* done  = (unsigned*)(ws + OFF_AC + 8);

  prep_kernel<<<512, 256, 0, stream>>>(x, xb, (uint4*)(ws + OFF_GA));
  fastap_main_kernel<<<dim3(NS / 64, NS / ROWCHUNK + 1), 256, 0, stream>>>(
      xb, labels, gS, gA, gPos);
  epilogue_kernel<<<NS / 256, 256, 0, stream>>>(gS, gA, gPos, accum, done, out);
}